// Round 6
// baseline (678.462 us; speedup 1.0000x reference)
//
#include <hip/hip_runtime.h>
#include <math.h>

// N=8192 all-pairs wind-influence graph. Output: [edge_attr f32 N*N][mask01 f32 N*N]
//
// Round 6: fill-like store pattern. R3/R4/R5 all ~183us kernel-region despite
// totally different inner loops => memory-floor at 2.9 TB/s, half of the 6.2
// TB/s the harness's own poison-fill sustains. Suspects: (T1) strided 4-KB
// chunk writes over 512-KB block footprints, (T6) per-wave 1-KB alternation
// between edge and mask streams 256 MB apart (HBM row thrash on shared
// channels). This round: block = one full row; edge row stored as one
// contiguous ascending 32-KB stream; mask packed to bits during the sweep and
// emitted after as a second contiguous ascending 32-KB burst. pair math is
// BIT-IDENTICAL to rounds 4/5 (same pair_body, same table values).
//
//   tab_i (N,12): s,c,hs,hc,hsl,hcl,sl,cl,swr,cwr,ws10,pad  (i-side, uniform)
//   tab_j (N,8):  s,c,hs,hc,hsl,hcl,sl,cl                   (j-side, dense 32B)

#define NN 8192
#define TI_FB 16
#define TJ_FB 1024
#define TABI_FLOATS (NN * 12)
#define TABJ_FLOATS (NN * 8)

typedef float f4v __attribute__((ext_vector_type(4)));

__global__ __launch_bounds__(256) void precomp_kernel(
    const float* __restrict__ pos,
    const float* __restrict__ wspd,
    const float* __restrict__ wdir,
    float* __restrict__ tab_i,         // (N,12)
    float* __restrict__ tab_j)         // (N,8)
{
    const int i = blockIdx.x * 256 + threadIdx.x;
    if (i >= NN) return;
    const float DEG2RAD = 0.017453292519943295f;
    float latr = pos[2 * i]     * DEG2RAD;
    float lonr = pos[2 * i + 1] * DEG2RAD;
    float wr   = wdir[i]        * DEG2RAD;
    float s, c, hs, hc, hsl, hcl, sl, cl, swr, cwr;
    sincosf(latr,        &s,   &c);
    sincosf(0.5f * latr, &hs,  &hc);
    sincosf(0.5f * lonr, &hsl, &hcl);
    sincosf(lonr,        &sl,  &cl);
    sincosf(wr,          &swr, &cwr);
    float* p = tab_i + i * 12;
    p[0] = s;   p[1] = c;   p[2]  = hs;  p[3]  = hc;
    p[4] = hsl; p[5] = hcl; p[6]  = sl;  p[7]  = cl;
    p[8] = swr; p[9] = cwr; p[10] = wspd[i] / 10.0f; p[11] = 0.0f;
    float* q = tab_j + i * 8;
    q[0] = s;   q[1] = c;   q[2] = hs;  q[3] = hc;
    q[4] = hsl; q[5] = hcl; q[6] = sl;  q[7] = cl;
}

__device__ __forceinline__ void pair_body(
    float is, float ic, float ihs, float ihc,
    float ihsl, float ihcl, float isl, float icl,
    float swr, float cwr, float ws10,
    float js, float jc, float jhs, float jhc,
    float jhsl, float jhcl, float jsl, float jcl,
    bool offdiag, float* ev, bool* mout)
{
    // haversine 'a' via cancellation-safe half-angle products
    float shlat = jhs * ihc - jhc * ihs;      // sin((lat2-lat1)/2)
    float shlon = jhsl * ihcl - jhcl * ihsl;  // sin((lon2-lon1)/2)
    float cc = ic * jc;
    float a = shlat * shlat + cc * (shlon * shlon);
    float ac = fminf(fmaxf(a, 1e-12f), 1.0f);

    // dist = 12742 * arcsin(s); 2-term series, exact-to-f32 in mask-true range
    float s = sqrtf(ac);
    float s2 = s * s;
    float dist = fmaf(s * s2, 2123.6667f, s * 12742.0f);

    // bearing vector
    float sdlon = jsl * icl - jcl * isl;
    float cdlon = jcl * icl + jsl * isl;
    float x = sdlon * jc;
    float y = ic * js - (is * jc) * cdlon;

    // alignment = cos(atan2(x,y) - wr)
    float num = y * cwr + x * swr;
    float h2  = x * x + y * y;
    float align = num * rsqrtf(h2);           // NaN on diagonal -> mask false

    float infl = align * ws10 * __expf(dist * -0.01f);
    bool m = offdiag && (dist <= 300.0f) && (infl > 0.3f);
    *ev = m ? infl : 0.0f;
    *mout = m;
}

__global__ __launch_bounds__(256) void row_kernel(
    const float* __restrict__ tab_i,   // (N,12)
    const float* __restrict__ tab_j,   // (N,8)
    float* __restrict__ out)           // 2*N*N floats
{
    const int i   = blockIdx.x;        // one block per output row
    const int tid = threadIdx.x;

    // i-side data: uniform across the block -> scalar loads
    const float* pi = tab_i + i * 12;
    const float is  = pi[0], ic  = pi[1], ihs = pi[2], ihc = pi[3];
    const float ihsl= pi[4], ihcl= pi[5], isl = pi[6], icl = pi[7];
    const float swr = pi[8], cwr = pi[9], ws10= pi[10];

    const size_t row = (size_t)i * NN;
    unsigned maskbits = 0;

    #pragma unroll 1
    for (int jc4 = 0; jc4 < 8; ++jc4) {
        const int jbase = jc4 * 1024 + tid * 4;

        f4v ev;
        unsigned mb = 0;
        #pragma unroll
        for (int k = 0; k < 4; ++k) {
            const float4* q = (const float4*)tab_j + (size_t)(jbase + k) * 2;
            float4 A = q[0], B = q[1];
            float e; bool m;
            pair_body(is, ic, ihs, ihc, ihsl, ihcl, isl, icl, swr, cwr, ws10,
                      A.x, A.y, A.z, A.w, B.x, B.y, B.z, B.w,
                      (jbase + k) != i, &e, &m);
            ev[k] = e;
            mb |= (m ? 1u : 0u) << k;
        }

        // edge row: contiguous ascending stream across the block
        __builtin_nontemporal_store(ev, (f4v*)(out + row + jbase));
        maskbits |= mb << (jc4 * 4);
    }

    // mask row: second contiguous ascending burst (no fine-grained alternation)
    float* mrow = out + (size_t)NN * NN + row;
    #pragma unroll
    for (int jc4 = 0; jc4 < 8; ++jc4) {
        f4v mv;
        #pragma unroll
        for (int k = 0; k < 4; ++k)
            mv[k] = ((maskbits >> (jc4 * 4 + k)) & 1u) ? 1.0f : 0.0f;
        __builtin_nontemporal_store(mv, (f4v*)(mrow + jc4 * 1024 + tid * 4));
    }
}

// ---- fallback if ws too small: round-5 structure, in-thread trig ----
__global__ __launch_bounds__(256) void dyn_graph_kernel_fb(
    const float* __restrict__ pos,
    const float* __restrict__ wspd,
    const float* __restrict__ wdir,
    float* __restrict__ out)
{
    __shared__ __align__(16) float irow[TI_FB * 12];
    const int tid   = threadIdx.x;
    const int i0    = blockIdx.y * TI_FB;
    const int jbase = blockIdx.x * TJ_FB + tid * 4;
    const float DEG2RAD = 0.017453292519943295f;

    if (tid < TI_FB) {
        int i = i0 + tid;
        float latr = pos[2 * i]     * DEG2RAD;
        float lonr = pos[2 * i + 1] * DEG2RAD;
        float wr   = wdir[i]        * DEG2RAD;
        float s, c, hs, hc, hsl, hcl, sl, cl, swr, cwr;
        sincosf(latr,        &s,   &c);
        sincosf(0.5f * latr, &hs,  &hc);
        sincosf(0.5f * lonr, &hsl, &hcl);
        sincosf(lonr,        &sl,  &cl);
        sincosf(wr,          &swr, &cwr);
        float* p = &irow[tid * 12];
        p[0] = s;   p[1] = c;   p[2]  = hs;  p[3]  = hc;
        p[4] = hsl; p[5] = hcl; p[6]  = sl;  p[7]  = cl;
        p[8] = swr; p[9] = cwr; p[10] = wspd[i] / 10.0f; p[11] = 0.0f;
    }

    float4 p01 = *(const float4*)(pos + 2 * jbase);
    float4 p23 = *(const float4*)(pos + 2 * jbase + 4);
    float jlat[4] = { p01.x, p01.z, p23.x, p23.z };
    float jlon[4] = { p01.y, p01.w, p23.y, p23.w };
    float js[4], jcv[4], jhs[4], jhc[4], jhsl[4], jhcl[4], jsl[4], jcl[4];
    #pragma unroll
    for (int k = 0; k < 4; ++k) {
        float latr = jlat[k] * DEG2RAD;
        float lonr = jlon[k] * DEG2RAD;
        sincosf(latr,        &js[k],   &jcv[k]);
        sincosf(0.5f * latr, &jhs[k],  &jhc[k]);
        sincosf(0.5f * lonr, &jhsl[k], &jhcl[k]);
        sincosf(lonr,        &jsl[k],  &jcl[k]);
    }
    __syncthreads();

    #pragma unroll 1
    for (int r = 0; r < TI_FB; ++r) {
        const float4* p4 = (const float4*)&irow[r * 12];
        float4 A = p4[0], B = p4[1], C = p4[2];
        const int i = i0 + r;
        f4v ev, mv;
        #pragma unroll
        for (int k = 0; k < 4; ++k) {
            float e; bool m;
            pair_body(A.x, A.y, A.z, A.w, B.x, B.y, B.z, B.w, C.x, C.y, C.z,
                      js[k], jcv[k], jhs[k], jhc[k], jhsl[k], jhcl[k], jsl[k], jcl[k],
                      (jbase + k) != i, &e, &m);
            ev[k] = e; mv[k] = m ? 1.0f : 0.0f;
        }
        size_t idx = (size_t)i * NN + jbase;
        __builtin_nontemporal_store(ev, (f4v*)(out + idx));
        __builtin_nontemporal_store(mv, (f4v*)(out + (size_t)NN * NN + idx));
    }
}

extern "C" void kernel_launch(void* const* d_in, const int* in_sizes, int n_in,
                              void* d_out, int out_size, void* d_ws, size_t ws_size,
                              hipStream_t stream) {
    const float* pos  = (const float*)d_in[0];
    const float* wspd = (const float*)d_in[1];
    const float* wdir = (const float*)d_in[2];
    float* out = (float*)d_out;

    if (ws_size >= (size_t)(TABI_FLOATS + TABJ_FLOATS) * sizeof(float)) {
        float* tab_i = (float*)d_ws;
        float* tab_j = tab_i + TABI_FLOATS;
        precomp_kernel<<<dim3(NN / 256), dim3(256), 0, stream>>>(pos, wspd, wdir, tab_i, tab_j);
        row_kernel<<<dim3(NN), dim3(256), 0, stream>>>(tab_i, tab_j, out);
    } else {
        dim3 grid(NN / TJ_FB, NN / TI_FB);
        dyn_graph_kernel_fb<<<grid, dim3(256), 0, stream>>>(pos, wspd, wdir, out);
    }
}

// Round 7
// 555.293 us; speedup vs baseline: 1.2218x; 1.2218x over previous
//
#include <hip/hip_runtime.h>
#include <math.h>

// N=8192 all-pairs wind-influence graph. Output: [edge_attr f32 N*N][mask01 f32 N*N]
//
// Round 7: compact advancing write-window (T19).
//   R3/R4/R5: three different compute loops, identical 184 us = 2.9 TB/s writes
//   (exactly half of the 6.3 TB/s the harness's fill sustains) => floor is the
//   HBM-level spatial pattern of the write stream, not compute. Theory: ~2000
//   co-resident blocks with disjoint striped footprints fragment the
//   device-wide instantaneous write window across GBs -> DRAM row thrash.
//   Now: 512 blocks (2/CU, all co-resident). Block b owns j-chunk b&7 (j-side
//   regs loaded ONCE, reused 128 rows) and sweeps i-tiles s*64 + b/8, s=0..7.
//   At each s the whole device writes one compact 32-MB edge window + its mask
//   twin, advancing linearly -- fill-like behavior at the channels.
//   pair_body is BIT-IDENTICAL to rounds 4/5/6 -> absmax unchanged.
//
//   tab_i (N,12): s,c,hs,hc,hsl,hcl,sl,cl,swr,cwr,ws10,pad  (i-side, uniform)
//   tab_j (N,8):  s,c,hs,hc,hsl,hcl,sl,cl                   (j-side, dense 32B)

#define NN 8192
#define TI_FB 16
#define TJ_FB 1024
#define TABI_FLOATS (NN * 12)
#define TABJ_FLOATS (NN * 8)

typedef float f4v __attribute__((ext_vector_type(4)));

__global__ __launch_bounds__(256) void precomp_kernel(
    const float* __restrict__ pos,
    const float* __restrict__ wspd,
    const float* __restrict__ wdir,
    float* __restrict__ tab_i,         // (N,12)
    float* __restrict__ tab_j)         // (N,8)
{
    const int i = blockIdx.x * 256 + threadIdx.x;
    if (i >= NN) return;
    const float DEG2RAD = 0.017453292519943295f;
    float latr = pos[2 * i]     * DEG2RAD;
    float lonr = pos[2 * i + 1] * DEG2RAD;
    float wr   = wdir[i]        * DEG2RAD;
    float s, c, hs, hc, hsl, hcl, sl, cl, swr, cwr;
    sincosf(latr,        &s,   &c);
    sincosf(0.5f * latr, &hs,  &hc);
    sincosf(0.5f * lonr, &hsl, &hcl);
    sincosf(lonr,        &sl,  &cl);
    sincosf(wr,          &swr, &cwr);
    float* p = tab_i + i * 12;
    p[0] = s;   p[1] = c;   p[2]  = hs;  p[3]  = hc;
    p[4] = hsl; p[5] = hcl; p[6]  = sl;  p[7]  = cl;
    p[8] = swr; p[9] = cwr; p[10] = wspd[i] / 10.0f; p[11] = 0.0f;
    float* q = tab_j + i * 8;
    q[0] = s;   q[1] = c;   q[2] = hs;  q[3] = hc;
    q[4] = hsl; q[5] = hcl; q[6] = sl;  q[7] = cl;
}

__device__ __forceinline__ void pair_body(
    float is, float ic, float ihs, float ihc,
    float ihsl, float ihcl, float isl, float icl,
    float swr, float cwr, float ws10,
    float js, float jc, float jhs, float jhc,
    float jhsl, float jhcl, float jsl, float jcl,
    bool offdiag, float* ev, float* mv)
{
    // haversine 'a' via cancellation-safe half-angle products
    float shlat = jhs * ihc - jhc * ihs;      // sin((lat2-lat1)/2)
    float shlon = jhsl * ihcl - jhcl * ihsl;  // sin((lon2-lon1)/2)
    float cc = ic * jc;
    float a = shlat * shlat + cc * (shlon * shlon);
    float ac = fminf(fmaxf(a, 1e-12f), 1.0f);

    // dist = 12742 * arcsin(s); 2-term series, exact-to-f32 in mask-true range
    float s = sqrtf(ac);
    float s2 = s * s;
    float dist = fmaf(s * s2, 2123.6667f, s * 12742.0f);

    // bearing vector
    float sdlon = jsl * icl - jcl * isl;
    float cdlon = jcl * icl + jsl * isl;
    float x = sdlon * jc;
    float y = ic * js - (is * jc) * cdlon;

    // alignment = cos(atan2(x,y) - wr)
    float num = y * cwr + x * swr;
    float h2  = x * x + y * y;
    float align = num * rsqrtf(h2);           // NaN on diagonal -> mask false

    float infl = align * ws10 * __expf(dist * -0.01f);
    bool m = offdiag && (dist <= 300.0f) && (infl > 0.3f);
    *ev = m ? infl : 0.0f;
    *mv = m ? 1.0f : 0.0f;
}

__global__ __launch_bounds__(256) void sweep_kernel(
    const float* __restrict__ tab_i,   // (N,12)
    const float* __restrict__ tab_j,   // (N,8)
    float* __restrict__ out)           // 2*N*N floats
{
    const int b   = blockIdx.x;        // 0..511
    const int tid = threadIdx.x;
    const int c   = b & 7;             // fixed j-chunk for this block
    const int jbase = c * 1024 + tid * 4;

    // ---- j-side values: loaded ONCE, reused across 8*16 = 128 i-rows ----
    float js[4], jc[4], jhs[4], jhc[4], jhsl[4], jhcl[4], jsl[4], jcl[4];
    #pragma unroll
    for (int k = 0; k < 4; ++k) {
        const float4* q = (const float4*)tab_j + (size_t)(jbase + k) * 2;
        float4 A = q[0], B = q[1];
        js[k]   = A.x; jc[k]   = A.y; jhs[k] = A.z; jhc[k] = A.w;
        jhsl[k] = B.x; jhcl[k] = B.y; jsl[k] = B.z; jcl[k] = B.w;
    }

    // ---- sweep: at step s ALL blocks write rows [s*1024, s*1024+1024) ----
    #pragma unroll 1
    for (int s = 0; s < 8; ++s) {
        const int i0 = (s * 64 + (b >> 3)) * 16;

        #pragma unroll 1
        for (int r = 0; r < 16; ++r) {
            const int i = i0 + r;
            const float4* p4 = (const float4*)(tab_i + (size_t)i * 12); // block-uniform -> scalar loads
            float4 A = p4[0], B = p4[1], C = p4[2];

            f4v ev, mv;
            #pragma unroll
            for (int k = 0; k < 4; ++k) {
                float e, m;
                pair_body(A.x, A.y, A.z, A.w, B.x, B.y, B.z, B.w, C.x, C.y, C.z,
                          js[k], jc[k], jhs[k], jhc[k], jhsl[k], jhcl[k], jsl[k], jcl[k],
                          (jbase + k) != i, &e, &m);
                ev[k] = e; mv[k] = m;
            }

            size_t idx = (size_t)i * NN + jbase;
            __builtin_nontemporal_store(ev, (f4v*)(out + idx));
            __builtin_nontemporal_store(mv, (f4v*)(out + (size_t)NN * NN + idx));
        }
    }
}

// ---- fallback if ws too small: round-5 structure, in-thread trig ----
__global__ __launch_bounds__(256) void dyn_graph_kernel_fb(
    const float* __restrict__ pos,
    const float* __restrict__ wspd,
    const float* __restrict__ wdir,
    float* __restrict__ out)
{
    __shared__ __align__(16) float irow[TI_FB * 12];
    const int tid   = threadIdx.x;
    const int i0    = blockIdx.y * TI_FB;
    const int jbase = blockIdx.x * TJ_FB + tid * 4;
    const float DEG2RAD = 0.017453292519943295f;

    if (tid < TI_FB) {
        int i = i0 + tid;
        float latr = pos[2 * i]     * DEG2RAD;
        float lonr = pos[2 * i + 1] * DEG2RAD;
        float wr   = wdir[i]        * DEG2RAD;
        float s, c, hs, hc, hsl, hcl, sl, cl, swr, cwr;
        sincosf(latr,        &s,   &c);
        sincosf(0.5f * latr, &hs,  &hc);
        sincosf(0.5f * lonr, &hsl, &hcl);
        sincosf(lonr,        &sl,  &cl);
        sincosf(wr,          &swr, &cwr);
        float* p = &irow[tid * 12];
        p[0] = s;   p[1] = c;   p[2]  = hs;  p[3]  = hc;
        p[4] = hsl; p[5] = hcl; p[6]  = sl;  p[7]  = cl;
        p[8] = swr; p[9] = cwr; p[10] = wspd[i] / 10.0f; p[11] = 0.0f;
    }

    float4 p01 = *(const float4*)(pos + 2 * jbase);
    float4 p23 = *(const float4*)(pos + 2 * jbase + 4);
    float jlat[4] = { p01.x, p01.z, p23.x, p23.z };
    float jlon[4] = { p01.y, p01.w, p23.y, p23.w };
    float js[4], jcv[4], jhs[4], jhc[4], jhsl[4], jhcl[4], jsl[4], jcl[4];
    #pragma unroll
    for (int k = 0; k < 4; ++k) {
        float latr = jlat[k] * DEG2RAD;
        float lonr = jlon[k] * DEG2RAD;
        sincosf(latr,        &js[k],   &jcv[k]);
        sincosf(0.5f * latr, &jhs[k],  &jhc[k]);
        sincosf(0.5f * lonr, &jhsl[k], &jhcl[k]);
        sincosf(lonr,        &jsl[k],  &jcl[k]);
    }
    __syncthreads();

    #pragma unroll 1
    for (int r = 0; r < TI_FB; ++r) {
        const float4* p4 = (const float4*)&irow[r * 12];
        float4 A = p4[0], B = p4[1], C = p4[2];
        const int i = i0 + r;
        f4v ev, mv;
        #pragma unroll
        for (int k = 0; k < 4; ++k) {
            float e, m;
            pair_body(A.x, A.y, A.z, A.w, B.x, B.y, B.z, B.w, C.x, C.y, C.z,
                      js[k], jcv[k], jhs[k], jhc[k], jhsl[k], jhcl[k], jsl[k], jcl[k],
                      (jbase + k) != i, &e, &m);
            ev[k] = e; mv[k] = m;
        }
        size_t idx = (size_t)i * NN + jbase;
        __builtin_nontemporal_store(ev, (f4v*)(out + idx));
        __builtin_nontemporal_store(mv, (f4v*)(out + (size_t)NN * NN + idx));
    }
}

extern "C" void kernel_launch(void* const* d_in, const int* in_sizes, int n_in,
                              void* d_out, int out_size, void* d_ws, size_t ws_size,
                              hipStream_t stream) {
    const float* pos  = (const float*)d_in[0];
    const float* wspd = (const float*)d_in[1];
    const float* wdir = (const float*)d_in[2];
    float* out = (float*)d_out;

    if (ws_size >= (size_t)(TABI_FLOATS + TABJ_FLOATS) * sizeof(float)) {
        float* tab_i = (float*)d_ws;
        float* tab_j = tab_i + TABI_FLOATS;
        precomp_kernel<<<dim3(NN / 256), dim3(256), 0, stream>>>(pos, wspd, wdir, tab_i, tab_j);
        sweep_kernel<<<dim3(512), dim3(256), 0, stream>>>(tab_i, tab_j, out);
    } else {
        dim3 grid(NN / TJ_FB, NN / TI_FB);
        dyn_graph_kernel_fb<<<grid, dim3(256), 0, stream>>>(pos, wspd, wdir, out);
    }
}